// Round 5
// baseline (495.079 us; speedup 1.0000x reference)
//
#include <hip/hip_runtime.h>
#include <math.h>

#define HEADS 8
#define DK 64
#define DMODEL 512
#define BATCH 2
#define SEQ 2048
#define BH (BATCH * HEADS)

using f32x4 = __attribute__((ext_vector_type(4))) float;
using s16x8 = __attribute__((ext_vector_type(8))) short;

union FragU {
  uint4 u;
  s16x8 s;
  unsigned short us[8];
};

__device__ __forceinline__ unsigned short f32_to_bf16(float f) {
  unsigned int u = __float_as_uint(f);
  u += 0x7fffu + ((u >> 16) & 1u);
  return (unsigned short)(u >> 16);
}
__device__ __forceinline__ float bf16_to_f32(unsigned short h) {
  return __uint_as_float(((unsigned int)h) << 16);
}

// ---------------------------------------------------------------------------
// mask int32 [B][S][S] -> packed bits [B][S][S/32]. One block per row.
// ---------------------------------------------------------------------------
__global__ __launch_bounds__(256) void pack_mask_kernel(
    const int* __restrict__ mask, unsigned int* __restrict__ bits) {
  const size_t row = blockIdx.x;  // B*S = 4096 rows
  const int wv = threadIdx.x >> 6, lane = threadIdx.x & 63;
  #pragma unroll
  for (int i = 0; i < 8; ++i) {
    const int c = wv * 512 + i * 64 + lane;
    unsigned long long bal = __ballot(mask[row * SEQ + c] != 0);
    if (lane == 0) {
      bits[row * 64 + (c >> 5)] = (unsigned int)bal;
      bits[row * 64 + (c >> 5) + 1] = (unsigned int)(bal >> 32);
    }
  }
}

// ---------------------------------------------------------------------------
// W[512][512] f32 -> Wt hi/lo bf16 in [n][k] (transposed) layout.
// ---------------------------------------------------------------------------
__global__ __launch_bounds__(256) void wsplit_kernel(
    const float* __restrict__ W, unsigned short* __restrict__ WtHi,
    unsigned short* __restrict__ WtLo) {
  __shared__ float t[64][65];
  const int k0 = blockIdx.x * 64, n0 = blockIdx.y * 64;
  const int tid = threadIdx.x;
  const int r = tid >> 2, c = (tid & 3) * 16;
  #pragma unroll
  for (int e = 0; e < 4; ++e) {
    f32x4 v = *(const f32x4*)&W[(size_t)(k0 + r) * DMODEL + n0 + c + e * 4];
    #pragma unroll
    for (int j = 0; j < 4; ++j) t[r][c + e * 4 + j] = v[j];
  }
  __syncthreads();
  const int rn = tid >> 2, ck = (tid & 3) * 16;
  #pragma unroll
  for (int half = 0; half < 2; ++half) {
    FragU hi, lo;
    #pragma unroll
    for (int e = 0; e < 8; ++e) {
      float x = t[ck + half * 8 + e][rn];
      unsigned short h = f32_to_bf16(x);
      hi.us[e] = h;
      lo.us[e] = f32_to_bf16(x - bf16_to_f32(h));
    }
    const size_t o = (size_t)(n0 + rn) * DMODEL + k0 + ck + half * 8;
    *(uint4*)&WtHi[o] = hi.u;
    *(uint4*)&WtLo[o] = lo.u;
  }
}

// ---------------------------------------------------------------------------
// MFMA projection GEMM (unchanged from R4).
// ---------------------------------------------------------------------------
template <int MODE>
__global__ __launch_bounds__(256) void proj_mfma_kernel(
    const float* __restrict__ X, const unsigned short* __restrict__ X16,
    const unsigned short* __restrict__ WtHi,
    const unsigned short* __restrict__ WtLo, const float* __restrict__ bias,
    float* __restrict__ Yf, unsigned short* __restrict__ Yhi,
    unsigned short* __restrict__ Ylo) {
  const int tid = threadIdx.x, wv = tid >> 6, lane = tid & 63;
  const int lr = lane & 15, lg = lane >> 4;
  const int m0 = blockIdx.x * 64 + wv * 16;
  const int n0 = blockIdx.y * 64;

  f32x4 acc[4] = {};
  for (int k0 = 0; k0 < 512; k0 += 64) {
    FragU ah[2], al[2];
    #pragma unroll
    for (int dc = 0; dc < 2; ++dc) {
      const size_t xi = (size_t)(m0 + lr) * DMODEL + k0 + dc * 32 + lg * 8;
      if (MODE == 3) {
        ah[dc].u = *(const uint4*)&X16[xi];
      } else {
        f32x4 x0 = *(const f32x4*)&X[xi];
        f32x4 x1 = *(const f32x4*)&X[xi + 4];
        #pragma unroll
        for (int t = 0; t < 4; ++t) {
          unsigned short h0 = f32_to_bf16(x0[t]);
          unsigned short h1 = f32_to_bf16(x1[t]);
          ah[dc].us[t] = h0;
          ah[dc].us[4 + t] = h1;
          al[dc].us[t] = f32_to_bf16(x0[t] - bf16_to_f32(h0));
          al[dc].us[4 + t] = f32_to_bf16(x1[t] - bf16_to_f32(h1));
        }
      }
    }
    #pragma unroll
    for (int jt = 0; jt < 4; ++jt) {
      #pragma unroll
      for (int dc = 0; dc < 2; ++dc) {
        const size_t wi =
            (size_t)(n0 + jt * 16 + lr) * DMODEL + k0 + dc * 32 + lg * 8;
        FragU bh, bl;
        bh.u = *(const uint4*)&WtHi[wi];
        bl.u = *(const uint4*)&WtLo[wi];
        acc[jt] = __builtin_amdgcn_mfma_f32_16x16x32_bf16(ah[dc].s, bh.s, acc[jt], 0, 0, 0);
        acc[jt] = __builtin_amdgcn_mfma_f32_16x16x32_bf16(ah[dc].s, bl.s, acc[jt], 0, 0, 0);
        if (MODE != 3)
          acc[jt] = __builtin_amdgcn_mfma_f32_16x16x32_bf16(al[dc].s, bh.s, acc[jt], 0, 0, 0);
      }
    }
  }

  #pragma unroll
  for (int jt = 0; jt < 4; ++jt) {
    const int n = n0 + jt * 16 + lr;
    const float bi = bias[n];
    #pragma unroll
    for (int r = 0; r < 4; ++r) {
      const int m = m0 + lg * 4 + r;
      const float v = acc[jt][r] + bi;
      if (MODE == 3) {
        Yf[(size_t)m * DMODEL + n] = v;
      } else {
        const int b = m >> 11, s = m & 2047;
        const int h = n >> 6, d = n & 63;
        const size_t idx = (((size_t)(b * HEADS + h) * SEQ) + s) * DK + d;
        unsigned short hi = f32_to_bf16(v);
        Yhi[idx] = hi;
        if (MODE == 1) Ylo[idx] = f32_to_bf16(v - bf16_to_f32(hi));
      }
    }
  }
}

// ---------------------------------------------------------------------------
// Vh[bh][s][d] bf16 -> Vt[bh][d][s] bf16
// ---------------------------------------------------------------------------
__global__ __launch_bounds__(256) void vtrans_kernel(
    const unsigned short* __restrict__ Vh, unsigned short* __restrict__ Vt) {
  __shared__ unsigned short t[64][72];
  const int tid = threadIdx.x;
  const int bh = blockIdx.y, s0 = blockIdx.x * 64;
  #pragma unroll
  for (int e = 0; e < 2; ++e) {
    int c = tid + e * 256;
    int r = c >> 3, c8 = (c & 7) * 8;
    *(uint4*)&t[r][c8] = *(const uint4*)&Vh[((size_t)bh * SEQ + s0 + r) * DK + c8];
  }
  __syncthreads();
  const int d = tid >> 2, sc0 = (tid & 3) * 16;
  #pragma unroll
  for (int e = 0; e < 16; ++e)
    Vt[((size_t)bh * DK + d) * SEQ + s0 + sc0 + e] = t[sc0 + e][d];
}

// ---------------------------------------------------------------------------
// K1 v2: split-bf16 QK^T stats. Q frags hoisted to registers (from L2, no
// LDS stage, no entry barrier). S held per jt-group of 4 (64 VGPR), two
// groups merged online. Waves own 128-col stripes as before.
// MFMA maps (verified): A[lr][lg*8+j]; B[lg*8+j][lr]; D[lg*4+r][lr].
// ---------------------------------------------------------------------------
__global__ __launch_bounds__(256) void stats_kernel(
    const unsigned short* __restrict__ Qhi, const unsigned short* __restrict__ Qlo,
    const unsigned short* __restrict__ Khi, const unsigned short* __restrict__ Klo,
    const unsigned int* __restrict__ bits, float* __restrict__ stats_part) {
  __shared__ float sm[4][64][2];
  const int bh = blockIdx.z, b = bh >> 3;
  const int q0 = blockIdx.x * 64, kb = blockIdx.y;
  const int tid = threadIdx.x;
  const int wv = tid >> 6, lane = tid & 63;
  const int lr = lane & 15, lg = lane >> 4;

  // Q frags in registers (A layout: row = q0 + i*16 + lr)
  FragU qh[4][2], ql[4][2];
  #pragma unroll
  for (int i = 0; i < 4; ++i)
    #pragma unroll
    for (int dc = 0; dc < 2; ++dc) {
      const size_t qi = ((size_t)bh * SEQ + q0 + i * 16 + lr) * DK + dc * 32 + lg * 8;
      qh[i][dc].u = *(const uint4*)&Qhi[qi];
      ql[i][dc].u = *(const uint4*)&Qlo[qi];
    }

  const int kw0 = kb * 512 + wv * 128;
  float mf[4][4], lf[4][4];

  #pragma unroll
  for (int jg = 0; jg < 2; ++jg) {
    f32x4 s[4][4] = {};  // [jt4][i]
    #pragma unroll
    for (int jt4 = 0; jt4 < 4; ++jt4) {
      const int jt = jg * 4 + jt4;
      FragU kh[2], kl[2];
      #pragma unroll
      for (int dc = 0; dc < 2; ++dc) {
        const size_t kidx =
            ((size_t)bh * SEQ + kw0 + jt * 16 + lr) * DK + dc * 32 + lg * 8;
        kh[dc].u = *(const uint4*)&Khi[kidx];
        kl[dc].u = *(const uint4*)&Klo[kidx];
      }
      #pragma unroll
      for (int i = 0; i < 4; ++i) {
        #pragma unroll
        for (int dc = 0; dc < 2; ++dc) {
          s[jt4][i] = __builtin_amdgcn_mfma_f32_16x16x32_bf16(qh[i][dc].s, kh[dc].s, s[jt4][i], 0, 0, 0);
          s[jt4][i] = __builtin_amdgcn_mfma_f32_16x16x32_bf16(qh[i][dc].s, kl[dc].s, s[jt4][i], 0, 0, 0);
          s[jt4][i] = __builtin_amdgcn_mfma_f32_16x16x32_bf16(ql[i][dc].s, kh[dc].s, s[jt4][i], 0, 0, 0);
        }
      }
    }
    // reduce this jt-group, merge online into mf/lf
    #pragma unroll
    for (int i = 0; i < 4; ++i) {
      #pragma unroll
      for (int r = 0; r < 4; ++r) {
        const int q = q0 + i * 16 + lg * 4 + r;
        const size_t base = ((size_t)b * SEQ + q) * 64 + (kw0 >> 5);
        float vals[4];
        #pragma unroll
        for (int jt4 = 0; jt4 < 4; ++jt4) {
          const int jt = jg * 4 + jt4;
          const unsigned int w = bits[base + (jt >> 1)];
          const bool keep = (w >> (((jt & 1) << 4) + lr)) & 1;
          vals[jt4] = keep ? s[jt4][i][r] * 0.125f : -10000.0f;
        }
        float m = fmaxf(fmaxf(vals[0], vals[1]), fmaxf(vals[2], vals[3]));
        #pragma unroll
        for (int off = 1; off < 16; off <<= 1) m = fmaxf(m, __shfl_xor(m, off));
        float l = 0.f;
        #pragma unroll
        for (int jt4 = 0; jt4 < 4; ++jt4) l += __expf(vals[jt4] - m);
        #pragma unroll
        for (int off = 1; off < 16; off <<= 1) l += __shfl_xor(l, off);
        if (jg == 0) {
          mf[i][r] = m;
          lf[i][r] = l;
        } else {
          const float mn = fmaxf(mf[i][r], m);
          lf[i][r] = lf[i][r] * __expf(mf[i][r] - mn) + l * __expf(m - mn);
          mf[i][r] = mn;
        }
      }
    }
  }

  #pragma unroll
  for (int i = 0; i < 4; ++i)
    #pragma unroll
    for (int r = 0; r < 4; ++r)
      if (lr == 0) {
        sm[wv][i * 16 + lg * 4 + r][0] = mf[i][r];
        sm[wv][i * 16 + lg * 4 + r][1] = lf[i][r];
      }
  __syncthreads();
  if (tid < 64) {
    float m = sm[0][tid][0];
    #pragma unroll
    for (int w = 1; w < 4; ++w) m = fmaxf(m, sm[w][tid][0]);
    float l = 0.f;
    #pragma unroll
    for (int w = 0; w < 4; ++w) l += sm[w][tid][1] * __expf(sm[w][tid][0] - m);
    const size_t o = ((size_t)bh * SEQ + q0 + tid) * 8 + (size_t)kb * 2;
    stats_part[o] = m;
    stats_part[o + 1] = l;
  }
}

// ---------------------------------------------------------------------------
// Combine 4 k-block partials per row -> (m, 1/l)
// ---------------------------------------------------------------------------
__global__ __launch_bounds__(256) void stats_reduce_kernel(
    const float* __restrict__ part, float* __restrict__ fin) {
  const int idx = blockIdx.x * 256 + threadIdx.x;  // 32768 rows
  const float* p = part + (size_t)idx * 8;
  float m = p[0];
  #pragma unroll
  for (int i = 1; i < 4; ++i) m = fmaxf(m, p[i * 2]);
  float l = 0.f;
  #pragma unroll
  for (int i = 0; i < 4; ++i) l += p[i * 2 + 1] * __expf(p[i * 2] - m);
  fin[(size_t)idx * 2] = m;
  fin[(size_t)idx * 2 + 1] = 1.0f / l;
}

// ---------------------------------------------------------------------------
// K3 v2: wave-private kt tiles. Block = 64 q-rows, 8 waves; wave wv handles
// kt = wv + 8t (t=0..3). K/V frags straight from L2 into registers — no
// K LDS, no main-loop barriers. S recomputed with MFMA order bit-identical
// to stats (dc-inner hh,hl,lh). p written once (the attn output); p->bf16
// transposed through wave-private pbuf for the PV A-operand. PV partials
// tree-reduced across the 8 waves via LDS at the end.
// ---------------------------------------------------------------------------
__global__ __launch_bounds__(512) void pv_fused_kernel(
    const unsigned short* __restrict__ Qhi, const unsigned short* __restrict__ Qlo,
    const unsigned short* __restrict__ Khi, const unsigned short* __restrict__ Klo,
    const unsigned int* __restrict__ bits, const float* __restrict__ statsf,
    const unsigned short* __restrict__ Vt, float* __restrict__ attn,
    unsigned short* __restrict__ ctx16) {
  __shared__ unsigned short pbuf[8][64 * 72];  // 73.7 KB, wave-private tiles
  const int bh = blockIdx.y, b = bh >> 3, h = bh & 7;
  const int tid = threadIdx.x, wv = tid >> 6, lane = tid & 63;
  const int lr = lane & 15, lg = lane >> 4;
  const int q0 = blockIdx.x * 64;

  // Q frags (A layout: row = q0 + i*16 + lr)
  FragU qh[4][2], ql[4][2];
  #pragma unroll
  for (int i = 0; i < 4; ++i)
    #pragma unroll
    for (int dc = 0; dc < 2; ++dc) {
      const size_t qi = ((size_t)bh * SEQ + q0 + i * 16 + lr) * DK + dc * 32 + lg * 8;
      qh[i][dc].u = *(const uint4*)&Qhi[qi];
      ql[i][dc].u = *(const uint4*)&Qlo[qi];
    }
  // per-row stats (D layout rows: q = q0 + i*16 + lg*4 + r)
  float mr[4][4], il[4][4];
  #pragma unroll
  for (int i = 0; i < 4; ++i)
    #pragma unroll
    for (int r = 0; r < 4; ++r) {
      const size_t si = ((size_t)bh * SEQ + q0 + i * 16 + lg * 4 + r) * 2;
      mr[i][r] = statsf[si];
      il[i][r] = statsf[si + 1];
    }

  float* ab = attn + (size_t)bh * SEQ * SEQ;
  const unsigned int* bb = bits + ((size_t)b * SEQ + q0) * 64;
  unsigned short* pb = pbuf[wv];
  f32x4 acc[4][4] = {};  // [i][dt]

  #pragma unroll 1
  for (int t = 0; t < 4; ++t) {
    const int kbase = (wv + t * 8) * 64;
    #pragma unroll
    for (int jt = 0; jt < 4; ++jt) {
      FragU kh[2], kl[2];
      #pragma unroll
      for (int dc = 0; dc < 2; ++dc) {
        const size_t kidx =
            ((size_t)bh * SEQ + kbase + jt * 16 + lr) * DK + dc * 32 + lg * 8;
        kh[dc].u = *(const uint4*)&Khi[kidx];
        kl[dc].u = *(const uint4*)&Klo[kidx];
      }
      #pragma unroll
      for (int i = 0; i < 4; ++i) {
        f32x4 s = {};
        #pragma unroll
        for (int dc = 0; dc < 2; ++dc) {
          s = __builtin_amdgcn_mfma_f32_16x16x32_bf16(qh[i][dc].s, kh[dc].s, s, 0, 0, 0);
          s = __builtin_amdgcn_mfma_f32_16x16x32_bf16(qh[i][dc].s, kl[dc].s, s, 0, 0, 0);
          s = __builtin_amdgcn_mfma_f32_16x16x32_bf16(ql[i][dc].s, kh[dc].s, s, 0, 0, 0);
        }
        #pragma unroll
        for (int r = 0; r < 4; ++r) {
          const int qrow = i * 16 + lg * 4 + r;
          const unsigned int w = bb[qrow * 64 + (kbase >> 5) + (jt >> 1)];
          const bool keep = (w >> (((jt & 1) << 4) + lr)) & 1;
          const float sv = keep ? s[r] * 0.125f : -10000.0f;
          const float p = __expf(sv - mr[i][r]) * il[i][r];
          ab[(q0 + qrow) * SEQ + kbase + jt * 16 + lr] = p;
          pb[qrow * 72 + jt * 16 + lr] = f32_to_bf16(p);
        }
      }
    }
    // PV: A = p (row=lr, k=lg*8+j) from pbuf; B = V[k][d] from Vt[d][k]
    #pragma unroll
    for (int i = 0; i < 4; ++i)
      #pragma unroll
      for (int dc2 = 0; dc2 < 2; ++dc2) {
        FragU pa;
        pa.u = *(const uint4*)&pb[(i * 16 + lr) * 72 + dc2 * 32 + lg * 8];
        #pragma unroll
        for (int dt = 0; dt < 4; ++dt) {
          FragU bv;
          bv.u = *(const uint4*)&Vt[((size_t)bh * DK + dt * 16 + lr) * SEQ + kbase +
                                    dc2 * 32 + lg * 8];
          acc[i][dt] = __builtin_amdgcn_mfma_f32_16x16x32_bf16(pa.s, bv.s, acc[i][dt], 0, 0, 0);
        }
      }
  }

  // tree-reduce the 8 waves' PV partials via LDS (reuse pbuf as f32)
  float* red = (float*)&pbuf[0][0];
  #pragma unroll 1
  for (int ofs = 4; ofs > 0; ofs >>= 1) {
    __syncthreads();
    if (wv >= ofs && wv < 2 * ofs) {
      float* dst = red + (size_t)(wv - ofs) * 4096;
      #pragma unroll
      for (int i = 0; i < 4; ++i)
        #pragma unroll
        for (int dt = 0; dt < 4; ++dt)
          *(f32x4*)&dst[(i * 4 + dt) * 256 + lane * 4] = acc[i][dt];
    }
    __syncthreads();
    if (wv < ofs) {
      const float* src = red + (size_t)wv * 4096;
      #pragma unroll
      for (int i = 0; i < 4; ++i)
        #pragma unroll
        for (int dt = 0; dt < 4; ++dt) {
          f32x4 v = *(const f32x4*)&src[(i * 4 + dt) * 256 + lane * 4];
          acc[i][dt] += v;
        }
    }
  }

  if (wv == 0) {
    #pragma unroll
    for (int i = 0; i < 4; ++i)
      #pragma unroll
      for (int dt = 0; dt < 4; ++dt)
        #pragma unroll
        for (int r = 0; r < 4; ++r) {
          const int q = q0 + i * 16 + lg * 4 + r;
          ctx16[((size_t)(b * SEQ + q)) * DMODEL + h * DK + dt * 16 + lr] =
              f32_to_bf16(acc[i][dt][r]);
        }
  }
}

// ---------------------------------------------------------------------------
extern "C" void kernel_launch(void* const* d_in, const int* in_sizes, int n_in,
                              void* d_out, int out_size, void* d_ws,
                              size_t ws_size, hipStream_t stream) {
  const float* q = (const float*)d_in[0];
  const float* k = (const float*)d_in[1];
  const float* v = (const float*)d_in[2];
  const int* mask = (const int*)d_in[3];
  const float* Wq = (const float*)d_in[4];
  const float* bq = (const float*)d_in[5];
  const float* Wk = (const float*)d_in[6];
  const float* bk = (const float*)d_in[7];
  const float* Wv = (const float*)d_in[8];
  const float* bv = (const float*)d_in[9];
  const float* Wo = (const float*)d_in[10];
  const float* bo = (const float*)d_in[11];

  float* out = (float*)d_out;
  float* attn = out + (size_t)BATCH * SEQ * DMODEL;

  char* w = (char*)d_ws;
  const size_t MB = 1u << 20;
  unsigned short* Qhi = (unsigned short*)(w + 0 * MB);
  unsigned short* Qlo = (unsigned short*)(w + 4 * MB);
  unsigned short* Khi = (unsigned short*)(w + 8 * MB);
  unsigned short* Klo = (unsigned short*)(w + 12 * MB);
  unsigned short* Vh16 = (unsigned short*)(w + 16 * MB);   // dead after vtrans
  unsigned short* Vt = (unsigned short*)(w + 20 * MB);
  unsigned int* bits = (unsigned int*)(w + 24 * MB);       // 1 MB
  float* stats_part = (float*)(w + 25 * MB);               // 1 MB
  float* statsf = (float*)(w + 26 * MB);                   // 256 KB
  unsigned short* WtHi = (unsigned short*)(w + 26 * MB + 256 * 1024);  // 512 KB
  unsigned short* WtLo = (unsigned short*)(w + 26 * MB + 768 * 1024);  // 512 KB
  unsigned short* ctx16 = (unsigned short*)(w + 16 * MB);  // overlays Vh16

  dim3 blk(256);
  pack_mask_kernel<<<dim3(BATCH * SEQ), blk, 0, stream>>>(mask, bits);

  wsplit_kernel<<<dim3(8, 8), blk, 0, stream>>>(Wq, WtHi, WtLo);
  proj_mfma_kernel<1><<<dim3(64, 8), blk, 0, stream>>>(q, nullptr, WtHi, WtLo, bq,
                                                       nullptr, Qhi, Qlo);
  wsplit_kernel<<<dim3(8, 8), blk, 0, stream>>>(Wk, WtHi, WtLo);
  proj_mfma_kernel<1><<<dim3(64, 8), blk, 0, stream>>>(k, nullptr, WtHi, WtLo, bk,
                                                       nullptr, Khi, Klo);
  wsplit_kernel<<<dim3(8, 8), blk, 0, stream>>>(Wv, WtHi, WtLo);
  proj_mfma_kernel<2><<<dim3(64, 8), blk, 0, stream>>>(v, nullptr, WtHi, WtLo, bv,
                                                       nullptr, Vh16, nullptr);
  vtrans_kernel<<<dim3(32, BH), blk, 0, stream>>>(Vh16, Vt);

  stats_kernel<<<dim3(32, 4, BH), blk, 0, stream>>>(Qhi, Qlo, Khi, Klo, bits, stats_part);
  stats_reduce_kernel<<<dim3(128), blk, 0, stream>>>(stats_part, statsf);
  pv_fused_kernel<<<dim3(32, BH), dim3(512), 0, stream>>>(Qhi, Qlo, Khi, Klo, bits,
                                                          statsf, Vt, attn, ctx16);

  wsplit_kernel<<<dim3(8, 8), blk, 0, stream>>>(Wo, WtHi, WtLo);
  proj_mfma_kernel<3><<<dim3(64, 8), blk, 0, stream>>>(nullptr, ctx16, WtHi, WtLo, bo,
                                                       out, nullptr, nullptr);
}